// Round 3
// baseline (5633.175 us; speedup 1.0000x reference)
//
#include <hip/hip_runtime.h>
#include <math.h>

#define N_NEU    2048
#define BB       64
#define TT       100
#define KIN      784
#define NIN_NEU  1024
#define N_OUT    10
#define NOUT_NEU 128
#define NBLK     256

typedef unsigned int u32;
typedef unsigned long long u64;
typedef unsigned char u8;

// ---------------- prep ----------------
__global__ void k_prep(const float* __restrict__ tau, double* __restrict__ d_syn,
                       double* __restrict__ e_tau, int* __restrict__ inv){
    int n = blockIdx.x * blockDim.x + threadIdx.x;
    if(n < N_NEU){
        double tv = (double)tau[n];
        d_syn[n] = exp(-1.0 / tv);
        e_tau[n] = 2.718281828459045 / tv;   // np.e / tau
        inv[n] = -1;
    }
}

__global__ void k_scatter(const int* __restrict__ idx, int* __restrict__ inv){
    int j = blockIdx.x * blockDim.x + threadIdx.x;
    if(j < NIN_NEU) inv[idx[j]] = j;
}

// zero barrier counters + both mask buffers (ws is poisoned 0xAA)
__global__ void k_init0(unsigned* __restrict__ bar, unsigned* __restrict__ masks){
    int i = blockIdx.x * blockDim.x + threadIdx.x;
    if(i < 1056) bar[i] = 0u;
    if(i < 8192) masks[i] = 0u;      // 2 x 16384 bytes
}

// ---------------- input projection GEMM (fp64 accum, fp32 LDS) ----------------
// proj[t][c][b] = sum_k X[t*64+b][k] * Win[c][k]
__global__ __launch_bounds__(256) void k_proj(const float* __restrict__ X, const float* __restrict__ Win,
                                              double* __restrict__ proj){
    __shared__ float As[32][68];
    __shared__ float Bs[32][68];
    const int r0 = blockIdx.x * 64;          // 64 rows == one t
    const int c0 = blockIdx.y * 64;
    const int t  = threadIdx.x;
    const int lr = t >> 2;          // 0..63
    const int lk = (t & 3) * 8;     // 0,8,16,24
    const int tx = t & 15, ty = t >> 4;
    double acc[4][4] = {};
    for(int k0 = 0; k0 < KIN; k0 += 32){
        int kk = k0 + lk;
        float a8[8], b8[8];
        if(kk + 8 <= KIN){
            const float* pa = X   + (size_t)(r0+lr)*KIN + kk;
            const float* pb = Win + (size_t)(c0+lr)*KIN + kk;
            float4 ra0 = *reinterpret_cast<const float4*>(pa);
            float4 ra1 = *reinterpret_cast<const float4*>(pa + 4);
            float4 rb0 = *reinterpret_cast<const float4*>(pb);
            float4 rb1 = *reinterpret_cast<const float4*>(pb + 4);
            a8[0]=ra0.x; a8[1]=ra0.y; a8[2]=ra0.z; a8[3]=ra0.w;
            a8[4]=ra1.x; a8[5]=ra1.y; a8[6]=ra1.z; a8[7]=ra1.w;
            b8[0]=rb0.x; b8[1]=rb0.y; b8[2]=rb0.z; b8[3]=rb0.w;
            b8[4]=rb1.x; b8[5]=rb1.y; b8[6]=rb1.z; b8[7]=rb1.w;
        } else {
            #pragma unroll
            for(int e=0;e<8;e++){ a8[e]=0.0f; b8[e]=0.0f; }
        }
        #pragma unroll
        for(int e=0;e<8;e++){ As[lk+e][lr] = a8[e]; Bs[lk+e][lr] = b8[e]; }
        __syncthreads();
        #pragma unroll
        for(int kkk=0;kkk<32;kkk++){
            float4 af = *reinterpret_cast<const float4*>(&As[kkk][ty*4]);
            float4 bf = *reinterpret_cast<const float4*>(&Bs[kkk][tx*4]);
            double a[4] = {(double)af.x,(double)af.y,(double)af.z,(double)af.w};
            double b[4] = {(double)bf.x,(double)bf.y,(double)bf.z,(double)bf.w};
            #pragma unroll
            for(int i=0;i<4;i++)
                #pragma unroll
                for(int j=0;j<4;j++)
                    acc[i][j] += a[i]*b[j];
        }
        __syncthreads();
    }
    const int tt = blockIdx.x;
    #pragma unroll
    for(int j=0;j<4;j++){
        int c = c0 + tx*4 + j;
        double* dst = proj + ((size_t)tt*NIN_NEU + c)*BB + ty*4;
        #pragma unroll
        for(int i=0;i<4;i++) dst[i] = acc[i][j];
    }
}

// ---------------- persistent simulation kernel ----------------
// 256 blocks x 512 threads; block g owns neurons [8g, 8g+8); thread = (n_loc=tid&7, b=tid>>3).
// W rows in LDS; state in registers; spikes exchanged via double-buffered global bitmask;
// one device-scope tree barrier per step.
__global__ __launch_bounds__(512, 2) void k_persist(
        const double* __restrict__ proj, const float* __restrict__ Wrec,
        const double* __restrict__ dsyn, const double* __restrict__ etau,
        const int* __restrict__ inv,
        u8* __restrict__ mask0, u8* __restrict__ mask1,
        unsigned* __restrict__ bar, double* __restrict__ cntout){
    __shared__ float Wl[2048][8];            // 64 KB: Wl[m][n_loc] = Wrec[8g+n_loc][m]
    const int g   = blockIdx.x;
    const int tid = threadIdx.x;
    const int n_loc = tid & 7;
    const int b     = tid >> 3;
    const int n     = g*8 + n_loc;

    // stage W rows (transposed)
    {
        int row  = tid >> 6;                 // 0..7
        int lane = tid & 63;
        const float* src = Wrec + (size_t)(g*8 + row)*N_NEU;
        #pragma unroll
        for(int q=0;q<8;q++){
            int fi = (q*64 + lane)*4;
            float4 v4 = *reinterpret_cast<const float4*>(src + fi);
            Wl[fi+0][row]=v4.x; Wl[fi+1][row]=v4.y; Wl[fi+2][row]=v4.z; Wl[fi+3][row]=v4.w;
        }
    }
    __syncthreads();

    const double ds = dsyn[n], et = etau[n];
    const double dasc = exp(-0.0125);
    const int jv = inv[n];
    double v=-60.0, psc=0.0, rise=0.0, asc=0.0, ref=0.0, spk=0.0, cntreg=0.0;

    for(int t=0;t<TT;t++){
        const u8* mR = (t & 1) ? mask1 : mask0;
        u8*       mW = (t & 1) ? mask0 : mask1;

        // ---- gather recurrent input from spike bitmask + LDS W ----
        double I = 0.0;
        const uint4* mrow = reinterpret_cast<const uint4*>(mR + (size_t)b*256);
        #pragma unroll 4
        for(int w4=0; w4<16; ++w4){
            uint4 mv = mrow[w4];
            u64 z0 = ((u64)mv.y << 32) | (u64)mv.x;
            u64 z1 = ((u64)mv.w << 32) | (u64)mv.z;
            int mb = w4*128;
            while(z0){ int bp = __ffsll(z0)-1; z0 &= z0-1; I += (double)Wl[mb+bp][n_loc]; }
            while(z1){ int bp = __ffsll(z1)-1; z1 &= z1-1; I += (double)Wl[mb+64+bp][n_loc]; }
        }
        if(jv >= 0) I += proj[((size_t)t*NIN_NEU + jv)*BB + b];

        // ---- neuron update (identical arithmetic to the verified k_update) ----
        double psc_n  = ds * (psc + rise);
        double rise_n = ds * rise + et * I;
        double asc_n  = dasc * asc + (-0.2) * spk;
        double active = (ref <= 0.0) ? 1.0 : 0.0;
        double dv  = (psc_n + asc_n + 0.12) / 2.0 - (v - (-60.0)) / 20.0;
        double v_n = v + active * dv;
        double x   = v_n - (-45.0);
        double spk_n = (x >= 0.0) ? active : 0.0;
        v_n = v_n - spk_n * 15.0;
        double ref_n = (spk_n > 0.0) ? 2.0 : fmax(ref - 1.0, 0.0);
        v = v_n; psc = psc_n; rise = rise_n; asc = asc_n; ref = ref_n; spk = spk_n;
        cntreg += spk_n;

        // ---- publish spikes: wave ballot -> 8 bytes (batches of this wave) ----
        u64 bal = __ballot(spk_n > 0.0);
        int lane = tid & 63;
        if(lane < 8){
            int bb = (tid >> 6)*8 + lane;
            mW[(size_t)bb*256 + g] = (u8)((bal >> (8*lane)) & 0xffULL);
        }

        // ---- grid barrier (tree: 32 leaves x 8 blocks, root) ----
        __syncthreads();
        if(tid == 0){
            __threadfence();
            int leaf = g >> 3;
            unsigned old = atomicAdd(&bar[leaf*32], 1u);
            if((old & 7u) == 7u) atomicAdd(&bar[1024], 1u);
            unsigned target = (unsigned)(t+1) * 32u;
            while(__hip_atomic_load(&bar[1024], __ATOMIC_ACQUIRE, __HIP_MEMORY_SCOPE_AGENT) < target){
                __builtin_amdgcn_s_sleep(2);
            }
        }
        __syncthreads();
        __threadfence();
    }

    cntout[(size_t)b*N_NEU + n] = cntreg;
}

// ---------------- readout ----------------
__global__ void k_final(const double* __restrict__ cnt, const int* __restrict__ oidx,
                        const float* __restrict__ Wout, float* __restrict__ out){
    int i = blockIdx.x * blockDim.x + threadIdx.x;
    if(i >= BB * N_OUT) return;
    int b = i / N_OUT, o = i - b * N_OUT;
    double accv = 0.0;
    for(int j=0;j<NOUT_NEU;j++){
        double rate = cnt[(size_t)b*N_NEU + oidx[j]] / 100.0;
        accv += rate * (double)Wout[o*NOUT_NEU + j];
    }
    out[i] = (float)accv;
}

extern "C" void kernel_launch(void* const* d_in, const int* in_sizes, int n_in,
                              void* d_out, int out_size, void* d_ws, size_t ws_size,
                              hipStream_t stream){
    const float* X    = (const float*)d_in[0];
    const float* Win  = (const float*)d_in[1];
    const float* Wrec = (const float*)d_in[2];
    const float* Wout = (const float*)d_in[3];
    const float* tau  = (const float*)d_in[4];
    const int*   iidx = (const int*)d_in[5];
    const int*   oidx = (const int*)d_in[6];
    float* out = (float*)d_out;

    char* w = (char*)d_ws;
    const size_t OFF_PROJ = 0;                                   // 52,428,800 B
    const size_t OFF_CNT  = OFF_PROJ + (size_t)TT*NIN_NEU*BB*8;  // 1,048,576 B
    const size_t OFF_MASK = OFF_CNT + (size_t)BB*N_NEU*8;        // 32,768 B (2 bufs)
    const size_t OFF_BAR  = OFF_MASK + 32768;                    // 4,352 B
    const size_t OFF_DS   = OFF_BAR + 4608;
    const size_t OFF_ET   = OFF_DS + N_NEU*8;
    const size_t OFF_INV  = OFF_ET + N_NEU*8;

    double* proj  = (double*)(w + OFF_PROJ);
    double* cnt   = (double*)(w + OFF_CNT);
    u8*     mask0 = (u8*)(w + OFF_MASK);
    u8*     mask1 = mask0 + 16384;
    unsigned* bar = (unsigned*)(w + OFF_BAR);
    double* dsyn  = (double*)(w + OFF_DS);
    double* etau  = (double*)(w + OFF_ET);
    int*    inv   = (int*)(w + OFF_INV);

    k_prep   <<<dim3(8),      dim3(256), 0, stream>>>(tau, dsyn, etau, inv);
    k_scatter<<<dim3(4),      dim3(256), 0, stream>>>(iidx, inv);
    k_init0  <<<dim3(32),     dim3(256), 0, stream>>>(bar, (unsigned*)mask0);
    k_proj   <<<dim3(100,16), dim3(256), 0, stream>>>(X, Win, proj);
    k_persist<<<dim3(NBLK),   dim3(512), 0, stream>>>(proj, Wrec, dsyn, etau, inv,
                                                      mask0, mask1, bar, cnt);
    k_final  <<<dim3(3),      dim3(256), 0, stream>>>(cnt, oidx, Wout, out);
}

// Round 4
// 877.880 us; speedup vs baseline: 6.4168x; 6.4168x over previous
//
#include <hip/hip_runtime.h>
#include <math.h>

#define N_NEU    2048
#define BB       64
#define TT       100
#define KIN      784
#define NIN_NEU  1024
#define N_OUT    10
#define NOUT_NEU 128

typedef unsigned int u32;
typedef unsigned long long u64;
typedef unsigned short u16;

// ---------------- prep ----------------
__global__ void k_prep(const float* __restrict__ tau, double* __restrict__ d_syn,
                       double* __restrict__ e_tau, int* __restrict__ inv){
    int n = blockIdx.x * blockDim.x + threadIdx.x;
    if(n < N_NEU){
        double tv = (double)tau[n];
        d_syn[n] = exp(-1.0 / tv);
        e_tau[n] = 2.718281828459045 / tv;   // np.e / tau
        inv[n] = -1;
    }
}

__global__ void k_scatter(const int* __restrict__ idx, int* __restrict__ inv){
    int j = blockIdx.x * blockDim.x + threadIdx.x;
    if(j < NIN_NEU) inv[idx[j]] = j;
}

// ---------------- W transpose: Wt[m][n] = Wrec[n][m] ----------------
__global__ __launch_bounds__(256) void k_tr(const float* __restrict__ Wrec, float* __restrict__ Wt){
    __shared__ float tile[32][33];
    int bx = blockIdx.x, by = blockIdx.y;
    int txx = threadIdx.x, tyy = threadIdx.y;          // (32, 8)
    #pragma unroll
    for(int j=0;j<4;j++)
        tile[tyy+8*j][txx] = Wrec[(size_t)(by*32 + tyy+8*j)*N_NEU + bx*32 + txx];
    __syncthreads();
    #pragma unroll
    for(int j=0;j<4;j++)
        Wt[(size_t)(bx*32 + tyy+8*j)*N_NEU + by*32 + txx] = tile[txx][tyy+8*j];
}

// ---------------- input projection GEMM (fp64 accum, fp32 LDS) ----------------
// proj[b][t][c] = sum_k X[t*64+b][k] * Win[c][k]
__global__ __launch_bounds__(256) void k_proj(const float* __restrict__ X, const float* __restrict__ Win,
                                              double* __restrict__ proj){
    __shared__ float As[32][68];
    __shared__ float Bs[32][68];
    const int r0 = blockIdx.x * 64;          // 64 rows == one t
    const int c0 = blockIdx.y * 64;
    const int t  = threadIdx.x;
    const int lr = t >> 2;          // 0..63
    const int lk = (t & 3) * 8;     // 0,8,16,24
    const int tx = t & 15, ty = t >> 4;
    double acc[4][4] = {};
    for(int k0 = 0; k0 < KIN; k0 += 32){
        int kk = k0 + lk;
        float a8[8], b8[8];
        if(kk + 8 <= KIN){
            const float* pa = X   + (size_t)(r0+lr)*KIN + kk;
            const float* pb = Win + (size_t)(c0+lr)*KIN + kk;
            float4 ra0 = *reinterpret_cast<const float4*>(pa);
            float4 ra1 = *reinterpret_cast<const float4*>(pa + 4);
            float4 rb0 = *reinterpret_cast<const float4*>(pb);
            float4 rb1 = *reinterpret_cast<const float4*>(pb + 4);
            a8[0]=ra0.x; a8[1]=ra0.y; a8[2]=ra0.z; a8[3]=ra0.w;
            a8[4]=ra1.x; a8[5]=ra1.y; a8[6]=ra1.z; a8[7]=ra1.w;
            b8[0]=rb0.x; b8[1]=rb0.y; b8[2]=rb0.z; b8[3]=rb0.w;
            b8[4]=rb1.x; b8[5]=rb1.y; b8[6]=rb1.z; b8[7]=rb1.w;
        } else {
            #pragma unroll
            for(int e=0;e<8;e++){ a8[e]=0.0f; b8[e]=0.0f; }
        }
        #pragma unroll
        for(int e=0;e<8;e++){ As[lk+e][lr] = a8[e]; Bs[lk+e][lr] = b8[e]; }
        __syncthreads();
        #pragma unroll
        for(int kkk=0;kkk<32;kkk++){
            float4 af = *reinterpret_cast<const float4*>(&As[kkk][ty*4]);
            float4 bf = *reinterpret_cast<const float4*>(&Bs[kkk][tx*4]);
            double a[4] = {(double)af.x,(double)af.y,(double)af.z,(double)af.w};
            double b[4] = {(double)bf.x,(double)bf.y,(double)bf.z,(double)bf.w};
            #pragma unroll
            for(int i=0;i<4;i++)
                #pragma unroll
                for(int j=0;j<4;j++)
                    acc[i][j] += a[i]*b[j];
        }
        __syncthreads();
    }
    const int tt = blockIdx.x;
    #pragma unroll
    for(int j=0;j<4;j++){
        int c = c0 + tx*4 + j;
        #pragma unroll
        for(int i=0;i<4;i++){
            int b = ty*4 + i;
            proj[((size_t)b*TT + tt)*NIN_NEU + c] = acc[i][j];
        }
    }
}

// ---------------- per-batch simulation: 64 blocks x 1024 threads ----------------
// Block b owns batch b. Thread owns neurons n0=tid, n1=tid+1024. No grid sync.
__global__ __launch_bounds__(1024) void k_sim(
        const double* __restrict__ proj, const float* __restrict__ Wt,
        const double* __restrict__ dsyn, const double* __restrict__ etau,
        const int* __restrict__ inv, double* __restrict__ cntout){
    __shared__ u32 words[64];
    __shared__ u16 list[N_NEU];
    __shared__ int cntS;

    const int b   = blockIdx.x;
    const int tid = threadIdx.x;
    const int n0 = tid, n1 = tid + 1024;
    const double* projB = proj + (size_t)b * TT * NIN_NEU;

    const double ds0 = dsyn[n0], et0 = etau[n0];
    const double ds1 = dsyn[n1], et1 = etau[n1];
    const int jv0 = inv[n0], jv1 = inv[n1];
    const double dasc = exp(-0.0125);

    double v0=-60.0, psc0=0.0, rise0=0.0, asc0=0.0, ref0=0.0, s0=0.0, c0=0.0;
    double v1=-60.0, psc1=0.0, rise1=0.0, asc1=0.0, ref1=0.0, s1=0.0, c1=0.0;

    if(tid == 0) cntS = 0;
    __syncthreads();

    for(int t=0;t<TT;t++){
        // issue proj loads early
        double p0 = (jv0 >= 0) ? projB[(size_t)t*NIN_NEU + jv0] : 0.0;
        double p1 = (jv1 >= 0) ? projB[(size_t)t*NIN_NEU + jv1] : 0.0;

        // ---- gather recurrent input over ordered spike list ----
        double I0 = 0.0, I1 = 0.0;
        const int cc = cntS;
        int i = 0;
        for(; i + 4 <= cc; i += 4){
            int m0 = list[i+0], m1 = list[i+1], m2 = list[i+2], m3 = list[i+3];
            const float* w0 = Wt + ((size_t)m0 << 11);
            const float* w1 = Wt + ((size_t)m1 << 11);
            const float* w2 = Wt + ((size_t)m2 << 11);
            const float* w3 = Wt + ((size_t)m3 << 11);
            float a0 = w0[n0], e0 = w0[n1];
            float a1 = w1[n0], e1 = w1[n1];
            float a2 = w2[n0], e2 = w2[n1];
            float a3 = w3[n0], e3 = w3[n1];
            I0 += (double)a0; I1 += (double)e0;
            I0 += (double)a1; I1 += (double)e1;
            I0 += (double)a2; I1 += (double)e2;
            I0 += (double)a3; I1 += (double)e3;
        }
        for(; i < cc; ++i){
            int m = list[i];
            const float* wr = Wt + ((size_t)m << 11);
            I0 += (double)wr[n0]; I1 += (double)wr[n1];
        }
        I0 += p0; I1 += p1;

        // ---- neuron updates (verified arithmetic) ----
        double psc_n0  = ds0 * (psc0 + rise0);
        double rise_n0 = ds0 * rise0 + et0 * I0;
        double asc_n0  = dasc * asc0 + (-0.2) * s0;
        double act0    = (ref0 <= 0.0) ? 1.0 : 0.0;
        double dv0  = (psc_n0 + asc_n0 + 0.12) / 2.0 - (v0 - (-60.0)) / 20.0;
        double v_n0 = v0 + act0 * dv0;
        double s_n0 = ((v_n0 - (-45.0)) >= 0.0) ? act0 : 0.0;
        v_n0 = v_n0 - s_n0 * 15.0;
        double ref_n0 = (s_n0 > 0.0) ? 2.0 : fmax(ref0 - 1.0, 0.0);
        v0 = v_n0; psc0 = psc_n0; rise0 = rise_n0; asc0 = asc_n0; ref0 = ref_n0; s0 = s_n0;
        c0 += s_n0;

        double psc_n1  = ds1 * (psc1 + rise1);
        double rise_n1 = ds1 * rise1 + et1 * I1;
        double asc_n1  = dasc * asc1 + (-0.2) * s1;
        double act1    = (ref1 <= 0.0) ? 1.0 : 0.0;
        double dv1  = (psc_n1 + asc_n1 + 0.12) / 2.0 - (v1 - (-60.0)) / 20.0;
        double v_n1 = v1 + act1 * dv1;
        double s_n1 = ((v_n1 - (-45.0)) >= 0.0) ? act1 : 0.0;
        v_n1 = v_n1 - s_n1 * 15.0;
        double ref_n1 = (s_n1 > 0.0) ? 2.0 : fmax(ref1 - 1.0, 0.0);
        v1 = v_n1; psc1 = psc_n1; rise1 = rise_n1; asc1 = asc_n1; ref1 = ref_n1; s1 = s_n1;
        c1 += s_n1;

        // ---- publish spikes into LDS bit-words via ballot ----
        u64 bal0 = __ballot(s_n0 > 0.0);
        u64 bal1 = __ballot(s_n1 > 0.0);
        if((tid & 63) == 0){
            int w2 = (tid >> 6) * 2;
            words[w2]      = (u32)bal0;
            words[w2+1]    = (u32)(bal0 >> 32);
            words[32+w2]   = (u32)bal1;
            words[33+w2]   = (u32)(bal1 >> 32);
        }
        __syncthreads();

        // ---- wave 0: ordered compaction into list ----
        if(tid < 64){
            u32 wv = words[tid];
            int c = __popc(wv);
            int incl = c;
            #pragma unroll
            for(int off=1; off<64; off<<=1){
                int x = __shfl_up(incl, off);
                if(tid >= off) incl += x;
            }
            int excl = incl - c;
            u32 z = wv;
            int base = tid * 32;
            while(z){
                int bp = __ffs(z) - 1;
                z &= z - 1;
                list[excl++] = (u16)(base + bp);
            }
            if(tid == 63) cntS = incl;
        }
        __syncthreads();
    }

    cntout[(size_t)b*N_NEU + n0] = c0;
    cntout[(size_t)b*N_NEU + n1] = c1;
}

// ---------------- readout ----------------
__global__ void k_final(const double* __restrict__ cnt, const int* __restrict__ oidx,
                        const float* __restrict__ Wout, float* __restrict__ out){
    int i = blockIdx.x * blockDim.x + threadIdx.x;
    if(i >= BB * N_OUT) return;
    int b = i / N_OUT, o = i - b * N_OUT;
    double accv = 0.0;
    for(int j=0;j<NOUT_NEU;j++){
        double rate = cnt[(size_t)b*N_NEU + oidx[j]] / 100.0;
        accv += rate * (double)Wout[o*NOUT_NEU + j];
    }
    out[i] = (float)accv;
}

extern "C" void kernel_launch(void* const* d_in, const int* in_sizes, int n_in,
                              void* d_out, int out_size, void* d_ws, size_t ws_size,
                              hipStream_t stream){
    const float* X    = (const float*)d_in[0];
    const float* Win  = (const float*)d_in[1];
    const float* Wrec = (const float*)d_in[2];
    const float* Wout = (const float*)d_in[3];
    const float* tau  = (const float*)d_in[4];
    const int*   iidx = (const int*)d_in[5];
    const int*   oidx = (const int*)d_in[6];
    float* out = (float*)d_out;

    char* w = (char*)d_ws;
    const size_t OFF_PROJ = 0;                                    // 52,428,800
    const size_t OFF_CNT  = OFF_PROJ + (size_t)TT*NIN_NEU*BB*8;   // 1,048,576
    const size_t OFF_WT   = OFF_CNT + (size_t)BB*N_NEU*8;         // 16,777,216
    const size_t OFF_DS   = OFF_WT + (size_t)N_NEU*N_NEU*4;
    const size_t OFF_ET   = OFF_DS + N_NEU*8;
    const size_t OFF_INV  = OFF_ET + N_NEU*8;

    double* proj  = (double*)(w + OFF_PROJ);
    double* cnt   = (double*)(w + OFF_CNT);
    float*  Wt    = (float*)(w + OFF_WT);
    double* dsyn  = (double*)(w + OFF_DS);
    double* etau  = (double*)(w + OFF_ET);
    int*    inv   = (int*)(w + OFF_INV);

    k_prep   <<<dim3(8),       dim3(256),    0, stream>>>(tau, dsyn, etau, inv);
    k_scatter<<<dim3(4),       dim3(256),    0, stream>>>(iidx, inv);
    k_tr     <<<dim3(64,64),   dim3(32,8),   0, stream>>>(Wrec, Wt);
    k_proj   <<<dim3(100,16),  dim3(256),    0, stream>>>(X, Win, proj);
    k_sim    <<<dim3(BB),      dim3(1024),   0, stream>>>(proj, Wt, dsyn, etau, inv, cnt);
    k_final  <<<dim3(3),       dim3(256),    0, stream>>>(cnt, oidx, Wout, out);
}